// Round 1
// baseline (304.162 us; speedup 1.0000x reference)
//
#include <hip/hip_runtime.h>

// VectorQuantizer on MI355X.
// latents: [64, 64, 32, 32] f32, embedding: [512, 64] f32.
// Outputs (concatenated in d_out): quantized_st [64,64,32,32] f32 (4194304), vq_loss scalar f32 (1).
// Numerically: quantized_st == embedding[argmin], vq_loss == 1.25 * mean((q - x)^2).

#define NUM_EMB 512
#define DIM 64
#define HW 1024            // 32*32
#define NPOS 65536         // 64 * 1024
#define TOTAL 4194304      // NPOS * DIM

// d_ws layout:
//   [0, 262144)        : int   ind[NPOS]
//   [262144, 264192)   : float ww[512]
//   [264192, 264200)   : double loss_acc

__global__ void ww_kernel(const float* __restrict__ emb, float* __restrict__ ww,
                          double* __restrict__ loss_acc) {
    const int k = blockIdx.x * blockDim.x + threadIdx.x;
    if (k == 0) *loss_acc = 0.0;   // zero the accumulator every call (ws is not re-poisoned)
    if (k < NUM_EMB) {
        const float4* row = (const float4*)(emb + k * DIM);
        float s = 0.f;
#pragma unroll
        for (int i = 0; i < DIM / 4; ++i) {
            float4 v = row[i];
            s += v.x * v.x + v.y * v.y + v.z * v.z + v.w * v.w;
        }
        ww[k] = s;
    }
}

// One thread = one spatial position. Whole embedding staged in 128 KiB LDS
// (broadcast ds_reads: all 64 lanes read the same w_k -> conflict-free).
// Grid = 256 blocks -> exactly 1 block (4 waves) per CU.
__global__ __launch_bounds__(256) void argmin_kernel(
    const float* __restrict__ latents, const float* __restrict__ emb,
    const float* __restrict__ ww, int* __restrict__ ind) {
    extern __shared__ float semb[];  // 32768 floats = 128 KiB
    const int tid = threadIdx.x;

    // cooperative stage: 8192 float4, 32 per thread, coalesced
    const float4* e4 = (const float4*)emb;
    float4* s4 = (float4*)semb;
#pragma unroll
    for (int i = 0; i < 32; ++i) s4[tid + i * 256] = e4[tid + i * 256];
    __syncthreads();

    const int n  = blockIdx.x * 256 + tid;
    const int b  = n >> 10;
    const int hw = n & 1023;
    // x_d = latents[b][d][hw]; consecutive lanes -> consecutive hw -> coalesced
    const float* xp = latents + (size_t)b * (DIM * HW) + hw;
    float x[DIM];
#pragma unroll
    for (int d = 0; d < DIM; ++d) x[d] = xp[d * HW];

    float best = 3.4e38f;
    int bidx = 0;
    for (int k = 0; k < NUM_EMB; ++k) {
        const float* w = semb + k * DIM;
        // 4 independent FMA chains to cover v_fmac 4-cycle dependent latency
        float a0 = 0.f, a1 = 0.f, a2 = 0.f, a3 = 0.f;
#pragma unroll
        for (int d = 0; d < DIM; d += 4) {
            a0 = fmaf(x[d + 0], w[d + 0], a0);
            a1 = fmaf(x[d + 1], w[d + 1], a1);
            a2 = fmaf(x[d + 2], w[d + 2], a2);
            a3 = fmaf(x[d + 3], w[d + 3], a3);
        }
        const float dot = (a0 + a1) + (a2 + a3);
        const float score = ww[k] - 2.0f * dot;   // ||x||^2 constant: drop it for argmin
        if (score < best) { best = score; bidx = k; }  // strict < keeps first index (jnp.argmin tie-break)
    }
    ind[n] = bidx;
}

// out[b,d,hw] = emb[ind[b*1024+hw]][d]; fused loss partials.
// Consecutive lanes -> consecutive hw: ind read coalesced, out write coalesced,
// emb gather is 128 KiB hot in L1/L2.
__global__ __launch_bounds__(256) void scatter_loss_kernel(
    const float* __restrict__ latents, const float* __restrict__ emb,
    const int* __restrict__ ind, float* __restrict__ out,
    double* __restrict__ loss_acc) {
    float acc = 0.f;
    const int stride = 2048 * 256;
    for (int idx = blockIdx.x * 256 + threadIdx.x; idx < TOTAL; idx += stride) {
        const int b  = idx >> 16;
        const int d  = (idx >> 10) & 63;
        const int hw = idx & 1023;
        const int k  = ind[(b << 10) + hw];
        const float q = emb[k * DIM + d];
        out[idx] = q;
        const float diff = q - latents[idx];
        acc = fmaf(diff, diff, acc);
    }
    // wave reduce (64 lanes), then one double atomic per wave
    double dacc = (double)acc;
#pragma unroll
    for (int off = 32; off; off >>= 1) dacc += __shfl_down(dacc, off, 64);
    if ((threadIdx.x & 63) == 0) atomicAdd(loss_acc, dacc);
}

__global__ void finalize_kernel(const double* __restrict__ loss_acc,
                                float* __restrict__ out) {
    // vq_loss = beta*mean + mean = 1.25 * mean
    out[TOTAL] = (float)(1.25 * (*loss_acc) / (double)TOTAL);
}

extern "C" void kernel_launch(void* const* d_in, const int* in_sizes, int n_in,
                              void* d_out, int out_size, void* d_ws, size_t ws_size,
                              hipStream_t stream) {
    const float* latents = (const float*)d_in[0];
    const float* emb     = (const float*)d_in[1];
    float* out = (float*)d_out;

    int*    ind      = (int*)d_ws;
    float*  ww       = (float*)((char*)d_ws + 262144);
    double* loss_acc = (double*)((char*)d_ws + 264192);

    // allow 128 KiB dynamic LDS (host-side attr set; not a stream op, capture-safe)
    static bool attr_done = false;
    if (!attr_done) {
        (void)hipFuncSetAttribute((const void*)argmin_kernel,
                                  hipFuncAttributeMaxDynamicSharedMemorySize, 131072);
        attr_done = true;
    }

    ww_kernel<<<2, 256, 0, stream>>>(emb, ww, loss_acc);
    argmin_kernel<<<256, 256, 131072, stream>>>(latents, emb, ww, ind);
    scatter_loss_kernel<<<2048, 256, 0, stream>>>(latents, emb, ind, out, loss_acc);
    finalize_kernel<<<1, 1, 0, stream>>>(loss_acc, out);
}

// Round 2
// 140.958 us; speedup vs baseline: 2.1578x; 2.1578x over previous
//
#include <hip/hip_runtime.h>

// VectorQuantizer on MI355X — MFMA argmin version.
// latents: [64, 64, 32, 32] f32, embedding: [512, 64] f32.
// d_out: quantized_st [64,64,32,32] f32 (4194304 elems) then vq_loss scalar f32.
// Math: quantized_st == embedding[argmin d2], vq_loss == 1.25 * mean((q - x)^2).
// argmin_k d2 == argmin_k (||w_k||^2 - 2 x.w_k)  (||x||^2 constant per position).

#define NUM_EMB 512
#define DIM 64
#define HW 1024
#define NPOS 65536
#define TOTAL 4194304

typedef __attribute__((ext_vector_type(8))) short bf16x8;
typedef __attribute__((ext_vector_type(4))) float f32x4;

// d_ws layout:
//   [0, 262144)        : int    ind[65536]
//   [262144, 327680)   : ushort wbf[512*64]  (bf16 bits of -2*W)
//   [327680, 329728)   : float  wwb[512]     (||w||^2 + 2.0 bias)
//   [329728, 329736)   : double loss_acc

__device__ __forceinline__ unsigned short f32_to_bf16_rne(float f) {
    unsigned int b = __builtin_bit_cast(unsigned int, f);
    return (unsigned short)((b + 0x7FFFu + ((b >> 16) & 1u)) >> 16);
}

__global__ __launch_bounds__(256) void prep_kernel(
    const float* __restrict__ emb, unsigned short* __restrict__ wbf,
    float* __restrict__ wwb, double* __restrict__ loss_acc) {
    const int t = blockIdx.x * 256 + threadIdx.x;
    if (t == 0) *loss_acc = 0.0;          // ws is not re-poisoned between replays
    if (t < NUM_EMB * DIM) wbf[t] = f32_to_bf16_rne(-2.0f * emb[t]);
    if (t < NUM_EMB) {
        const float* row = emb + t * DIM;
        float s = 0.f;
#pragma unroll
        for (int i = 0; i < DIM; ++i) s = fmaf(row[i], row[i], s);
        wwb[t] = s + 2.0f;                // +2 bias keeps packed scores positive
    }
}

// Each wave owns 32 positions (2 pos-tiles of 16). X fragments live in VGPRs
// for the whole k-loop; W fragments stream from L1/L2 (64 KB resident).
// Per 16-k tile: acc = mfma(a0, x0, wwb4); acc = mfma(a1, x1, acc)
//   -> acc[r] = ||w_k||^2 + 2 - 2 x.w_k  for k = k0 + g*4 + r, pos = pt*16 + c.
// Packed argmin: u32 = (score_bits & ~511) | k; running min_u32.
__global__ __launch_bounds__(256) void argmin_mfma_kernel(
    const float* __restrict__ latents, const unsigned short* __restrict__ wbf,
    const float* __restrict__ wwb, int* __restrict__ ind) {
    const int tid  = threadIdx.x;
    const int wave = tid >> 6;
    const int l    = tid & 63;
    const int c    = l & 15;   // tile col (position) / A row (k)
    const int g    = l >> 4;   // k-slot group

    const int n0  = blockIdx.x * 128 + wave * 32;  // 32 consecutive positions, same b
    const int b   = n0 >> 10;
    const int hw0 = n0 & 1023;

    // Load X fragments (bf16), pt in {0,1} pos-tiles, f in {0,1} K-halves.
    // Element j of frag: dim d = f*32 + g*8 + j, position p = pt*16 + c.
    bf16x8 xf[2][2];
    const float* xbase = latents + (size_t)b * (DIM * HW) + hw0;
#pragma unroll
    for (int pt = 0; pt < 2; ++pt) {
#pragma unroll
        for (int f = 0; f < 2; ++f) {
            const int d0 = f * 32 + g * 8;
            const int p  = pt * 16 + c;
            bf16x8 v;
#pragma unroll
            for (int j = 0; j < 8; ++j)
                v[j] = (short)f32_to_bf16_rne(xbase[(d0 + j) * HW + p]);
            xf[pt][f] = v;
        }
    }

    unsigned int best0 = 0xFFFFFFFFu, best1 = 0xFFFFFFFFu;
    const unsigned short* wp = wbf + c * DIM + g * 8;  // row k0+c, cols g*8..
    const float* wwp = wwb + g * 4;

#pragma unroll 4
    for (int k0 = 0; k0 < NUM_EMB; k0 += 16) {
        bf16x8 a0 = *(const bf16x8*)(wp);
        bf16x8 a1 = *(const bf16x8*)(wp + 32);
        f32x4 ww4 = *(const f32x4*)(wwp);
        wp  += 16 * DIM;
        wwp += 16;

        f32x4 acc0 = __builtin_amdgcn_mfma_f32_16x16x32_bf16(a0, xf[0][0], ww4, 0, 0, 0);
        acc0       = __builtin_amdgcn_mfma_f32_16x16x32_bf16(a1, xf[0][1], acc0, 0, 0, 0);
        f32x4 acc1 = __builtin_amdgcn_mfma_f32_16x16x32_bf16(a0, xf[1][0], ww4, 0, 0, 0);
        acc1       = __builtin_amdgcn_mfma_f32_16x16x32_bf16(a1, xf[1][1], acc1, 0, 0, 0);

        const unsigned int kb = (unsigned int)(k0 + g * 4);
#pragma unroll
        for (int r = 0; r < 4; ++r) {
            unsigned int t0 = (__builtin_bit_cast(unsigned int, acc0[r]) & 0xFFFFFE00u) | (kb + r);
            best0 = t0 < best0 ? t0 : best0;
            unsigned int t1 = (__builtin_bit_cast(unsigned int, acc1[r]) & 0xFFFFFE00u) | (kb + r);
            best1 = t1 < best1 ? t1 : best1;
        }
    }

    // reduce over the 4 k-groups (lanes c, c+16, c+32, c+48)
    unsigned int o;
    o = __shfl_xor(best0, 16); best0 = o < best0 ? o : best0;
    o = __shfl_xor(best0, 32); best0 = o < best0 ? o : best0;
    o = __shfl_xor(best1, 16); best1 = o < best1 ? o : best1;
    o = __shfl_xor(best1, 32); best1 = o < best1 ? o : best1;

    if (l < 16) {
        ind[n0 + l]      = (int)(best0 & 511u);
        ind[n0 + 16 + l] = (int)(best1 & 511u);
    }
}

// out[b,d,hw] = emb[ind[b*1024+hw]][d]; fused loss partials (exact f32 emb).
__global__ __launch_bounds__(256) void scatter_loss_kernel(
    const float* __restrict__ latents, const float* __restrict__ emb,
    const int* __restrict__ ind, float* __restrict__ out,
    double* __restrict__ loss_acc) {
    float acc = 0.f;
    const int stride = 2048 * 256;
    for (int idx = blockIdx.x * 256 + threadIdx.x; idx < TOTAL; idx += stride) {
        const int b  = idx >> 16;
        const int d  = (idx >> 10) & 63;
        const int hw = idx & 1023;
        const int k  = ind[(b << 10) + hw];
        const float q = emb[k * DIM + d];
        out[idx] = q;
        const float diff = q - latents[idx];
        acc = fmaf(diff, diff, acc);
    }
    double dacc = (double)acc;
#pragma unroll
    for (int off = 32; off; off >>= 1) dacc += __shfl_down(dacc, off, 64);
    if ((threadIdx.x & 63) == 0) atomicAdd(loss_acc, dacc);
}

__global__ void finalize_kernel(const double* __restrict__ loss_acc,
                                float* __restrict__ out) {
    out[TOTAL] = (float)(1.25 * (*loss_acc) / (double)TOTAL);
}

extern "C" void kernel_launch(void* const* d_in, const int* in_sizes, int n_in,
                              void* d_out, int out_size, void* d_ws, size_t ws_size,
                              hipStream_t stream) {
    const float* latents = (const float*)d_in[0];
    const float* emb     = (const float*)d_in[1];
    float* out = (float*)d_out;

    int*            ind      = (int*)d_ws;
    unsigned short* wbf      = (unsigned short*)((char*)d_ws + 262144);
    float*          wwb      = (float*)((char*)d_ws + 327680);
    double*         loss_acc = (double*)((char*)d_ws + 329728);

    prep_kernel<<<128, 256, 0, stream>>>(emb, wbf, wwb, loss_acc);
    argmin_mfma_kernel<<<512, 256, 0, stream>>>(latents, wbf, wwb, ind);
    scatter_loss_kernel<<<2048, 256, 0, stream>>>(latents, emb, ind, out, loss_acc);
    finalize_kernel<<<1, 1, 0, stream>>>(loss_acc, out);
}

// Round 3
// 39.667 us; speedup vs baseline: 7.6678x; 3.5535x over previous
//
#include <hip/hip_runtime.h>

// VectorQuantizer on MI355X — MFMA argmin + gather-friendly scatter.
// latents: [64, 64, 32, 32] f32, embedding: [512, 64] f32.
// d_out: quantized_st [64,64,32,32] f32 (4194304 elems) then vq_loss scalar f32.
// Math: quantized_st == embedding[argmin d2], vq_loss == 1.25 * mean((q - x)^2).

#define NUM_EMB 512
#define DIM 64
#define HW 1024
#define NPOS 65536
#define TOTAL 4194304
#define SCATTER_BLOCKS 2048

typedef __attribute__((ext_vector_type(8))) short bf16x8;
typedef __attribute__((ext_vector_type(4))) float f32x4;

// d_ws layout:
//   [0, 262144)        : int    ind[65536]
//   [262144, 327680)   : ushort wbf[512*64]   (bf16 bits of -2*W)
//   [327680, 329728)   : float  wwb[512]      (||w||^2 + 2.0 bias)
//   [331776, 462848)   : float  embT[64][512] (transposed embedding, f32 exact)
//   [462848, 471040)   : float  partial[2048] (per-block loss partials)

__device__ __forceinline__ unsigned short f32_to_bf16_rne(float f) {
    unsigned int b = __builtin_bit_cast(unsigned int, f);
    return (unsigned short)((b + 0x7FFFu + ((b >> 16) & 1u)) >> 16);
}

__global__ __launch_bounds__(256) void prep_kernel(
    const float* __restrict__ emb, unsigned short* __restrict__ wbf,
    float* __restrict__ wwb, float* __restrict__ embT) {
    const int t = blockIdx.x * 256 + threadIdx.x;  // 32768 threads
    if (t < NUM_EMB * DIM) {
        const float e = emb[t];
        wbf[t] = f32_to_bf16_rne(-2.0f * e);
        const int k = t >> 6, d = t & 63;
        embT[(d << 9) + k] = e;                    // transpose: embT[d][k]
    }
    if (t < NUM_EMB) {
        const float* row = emb + t * DIM;
        float s = 0.f;
#pragma unroll
        for (int i = 0; i < DIM; ++i) s = fmaf(row[i], row[i], s);
        wwb[t] = s + 2.0f;                         // +2 bias keeps packed scores positive
    }
}

// Each wave owns 32 positions (2 pos-tiles of 16). X fragments live in VGPRs
// for the whole k-loop; W fragments stream from L1/L2 (64 KB resident).
// acc[r] = ||w_k||^2 + 2 - 2 x.w_k  for k = k0 + g*4 + r, pos = pt*16 + c.
// Packed argmin: u32 = (score_bits & ~511) | k; running min_u32; strict <
// keeps the smallest k on ties (jnp.argmin tie-break).
__global__ __launch_bounds__(256) void argmin_mfma_kernel(
    const float* __restrict__ latents, const unsigned short* __restrict__ wbf,
    const float* __restrict__ wwb, int* __restrict__ ind) {
    const int tid  = threadIdx.x;
    const int wave = tid >> 6;
    const int l    = tid & 63;
    const int c    = l & 15;   // tile col (position) / A row (k)
    const int g    = l >> 4;   // k-slot group

    const int n0  = blockIdx.x * 128 + wave * 32;  // 32 consecutive positions, same b
    const int b   = n0 >> 10;
    const int hw0 = n0 & 1023;

    bf16x8 xf[2][2];
    const float* xbase = latents + (size_t)b * (DIM * HW) + hw0;
#pragma unroll
    for (int pt = 0; pt < 2; ++pt) {
#pragma unroll
        for (int f = 0; f < 2; ++f) {
            const int d0 = f * 32 + g * 8;
            const int p  = pt * 16 + c;
            bf16x8 v;
#pragma unroll
            for (int j = 0; j < 8; ++j)
                v[j] = (short)f32_to_bf16_rne(xbase[(d0 + j) * HW + p]);
            xf[pt][f] = v;
        }
    }

    unsigned int best0 = 0xFFFFFFFFu, best1 = 0xFFFFFFFFu;
    const unsigned short* wp = wbf + c * DIM + g * 8;
    const float* wwp = wwb + g * 4;

#pragma unroll 4
    for (int k0 = 0; k0 < NUM_EMB; k0 += 16) {
        bf16x8 a0 = *(const bf16x8*)(wp);
        bf16x8 a1 = *(const bf16x8*)(wp + 32);
        f32x4 ww4 = *(const f32x4*)(wwp);
        wp  += 16 * DIM;
        wwp += 16;

        f32x4 acc0 = __builtin_amdgcn_mfma_f32_16x16x32_bf16(a0, xf[0][0], ww4, 0, 0, 0);
        acc0       = __builtin_amdgcn_mfma_f32_16x16x32_bf16(a1, xf[0][1], acc0, 0, 0, 0);
        f32x4 acc1 = __builtin_amdgcn_mfma_f32_16x16x32_bf16(a0, xf[1][0], ww4, 0, 0, 0);
        acc1       = __builtin_amdgcn_mfma_f32_16x16x32_bf16(a1, xf[1][1], acc1, 0, 0, 0);

        const unsigned int kb = (unsigned int)(k0 + g * 4);
#pragma unroll
        for (int r = 0; r < 4; ++r) {
            unsigned int t0 = (__builtin_bit_cast(unsigned int, acc0[r]) & 0xFFFFFE00u) | (kb + r);
            best0 = t0 < best0 ? t0 : best0;
            unsigned int t1 = (__builtin_bit_cast(unsigned int, acc1[r]) & 0xFFFFFE00u) | (kb + r);
            best1 = t1 < best1 ? t1 : best1;
        }
    }

    unsigned int o;
    o = __shfl_xor(best0, 16); best0 = o < best0 ? o : best0;
    o = __shfl_xor(best0, 32); best0 = o < best0 ? o : best0;
    o = __shfl_xor(best1, 16); best1 = o < best1 ? o : best1;
    o = __shfl_xor(best1, 32); best1 = o < best1 ? o : best1;

    if (l < 16) {
        ind[n0 + l]      = (int)(best0 & 511u);
        ind[n0 + 16 + l] = (int)(best1 & 511u);
    }
}

// float4 over out: 4 consecutive idx share d and stay in one hw-row.
// Gather from embT[d][k]: all lanes of a wave share d -> one 2 KB row, L1-hot.
// No global atomics: wave reduce -> LDS -> one partial per block.
__global__ __launch_bounds__(256) void scatter_loss_kernel(
    const float* __restrict__ latents, const float* __restrict__ embT,
    const int* __restrict__ ind, float* __restrict__ out,
    float* __restrict__ partial) {
    float acc = 0.f;
    const int nvec = TOTAL / 4;                    // 1M float4 elements
    const int stride = SCATTER_BLOCKS * 256;
    for (int v = blockIdx.x * 256 + threadIdx.x; v < nvec; v += stride) {
        const int idx = v << 2;
        const int b  = idx >> 16;
        const int d  = (idx >> 10) & 63;
        const int hw = idx & 1023;
        const int4 k4 = *(const int4*)(ind + (b << 10) + hw);
        const float* er = embT + (d << 9);
        float4 q;
        q.x = er[k4.x]; q.y = er[k4.y]; q.z = er[k4.z]; q.w = er[k4.w];
        const float4 xl = *(const float4*)(latents + idx);
        *(float4*)(out + idx) = q;
        float d0 = q.x - xl.x, d1 = q.y - xl.y, d2 = q.z - xl.z, d3 = q.w - xl.w;
        acc = fmaf(d0, d0, acc); acc = fmaf(d1, d1, acc);
        acc = fmaf(d2, d2, acc); acc = fmaf(d3, d3, acc);
    }
#pragma unroll
    for (int off = 32; off; off >>= 1) acc += __shfl_xor(acc, off, 64);
    __shared__ float wsum[4];
    if ((threadIdx.x & 63) == 0) wsum[threadIdx.x >> 6] = acc;
    __syncthreads();
    if (threadIdx.x == 0)
        partial[blockIdx.x] = (wsum[0] + wsum[1]) + (wsum[2] + wsum[3]);
}

__global__ __launch_bounds__(256) void finalize_kernel(
    const float* __restrict__ partial, float* __restrict__ out) {
    double s = 0.0;
#pragma unroll
    for (int i = 0; i < SCATTER_BLOCKS / 256; ++i)
        s += (double)partial[threadIdx.x + i * 256];
#pragma unroll
    for (int off = 32; off; off >>= 1) s += __shfl_xor(s, off, 64);
    __shared__ double dsum[4];
    if ((threadIdx.x & 63) == 0) dsum[threadIdx.x >> 6] = s;
    __syncthreads();
    if (threadIdx.x == 0) {
        const double tot = (dsum[0] + dsum[1]) + (dsum[2] + dsum[3]);
        out[TOTAL] = (float)(1.25 * tot / (double)TOTAL);
    }
}

extern "C" void kernel_launch(void* const* d_in, const int* in_sizes, int n_in,
                              void* d_out, int out_size, void* d_ws, size_t ws_size,
                              hipStream_t stream) {
    const float* latents = (const float*)d_in[0];
    const float* emb     = (const float*)d_in[1];
    float* out = (float*)d_out;

    int*            ind     = (int*)d_ws;
    unsigned short* wbf     = (unsigned short*)((char*)d_ws + 262144);
    float*          wwb     = (float*)((char*)d_ws + 327680);
    float*          embT    = (float*)((char*)d_ws + 331776);
    float*          partial = (float*)((char*)d_ws + 462848);

    prep_kernel<<<128, 256, 0, stream>>>(emb, wbf, wwb, embT);
    argmin_mfma_kernel<<<512, 256, 0, stream>>>(latents, wbf, wwb, ind);
    scatter_loss_kernel<<<SCATTER_BLOCKS, 256, 0, stream>>>(latents, embT, ind, out, partial);
    finalize_kernel<<<1, 256, 0, stream>>>(partial, out);
}

// Round 4
// 38.047 us; speedup vs baseline: 7.9943x; 1.0426x over previous
//
#include <hip/hip_runtime.h>

// VectorQuantizer on MI355X — single fused MFMA argmin + quantize + loss.
// latents: [64, 64, 32, 32] f32, embedding: [512, 64] f32.
// d_out: quantized_st [64,64,32,32] f32 (4194304 elems) then vq_loss scalar f32.
// Math: quantized_st == embedding[argmin d2], vq_loss == 1.25 * mean((q - x)^2).
// Key identity: per position, sum_d (q-x)^2 = (winning_score - 2) + ||x||^2,
// where winning_score = ||w||^2 + 2 - 2 x.w is exactly the argmin score.

#define NUM_EMB 512
#define DIM 64
#define HW 1024
#define NPOS 65536
#define TOTAL 4194304
#define FUSED_BLOCKS 512

typedef __attribute__((ext_vector_type(8))) short bf16x8;
typedef __attribute__((ext_vector_type(4))) float f32x4;

// d_ws layout:
//   [0, 65536)        : ushort wbf[512*64]   (bf16 bits of -2*W)
//   [65536, 67584)    : float  wwb[512]      (||w||^2 + 2.0 bias)
//   [67584, 198656)   : float  embT[64][512] (transposed embedding, f32 exact)
//   [198656, 200704)  : float  partial[512]  (per-block loss partials)

__device__ __forceinline__ unsigned short f32_to_bf16_rne(float f) {
    unsigned int b = __builtin_bit_cast(unsigned int, f);
    return (unsigned short)((b + 0x7FFFu + ((b >> 16) & 1u)) >> 16);
}

__global__ __launch_bounds__(256) void prep_kernel(
    const float* __restrict__ emb, unsigned short* __restrict__ wbf,
    float* __restrict__ wwb, float* __restrict__ embT) {
    const int t = blockIdx.x * 256 + threadIdx.x;  // 32768 threads
    if (t < NUM_EMB * DIM) {
        const float e = emb[t];
        wbf[t] = f32_to_bf16_rne(-2.0f * e);
        const int k = t >> 6, d = t & 63;
        embT[(d << 9) + k] = e;                    // transpose: embT[d][k]
    }
    if (t < NUM_EMB) {
        const float* row = emb + t * DIM;
        float s = 0.f;
#pragma unroll
        for (int i = 0; i < DIM; ++i) s = fmaf(row[i], row[i], s);
        wwb[t] = s + 2.0f;                         // +2 bias keeps packed scores positive
    }
}

// One wave = 32 consecutive positions (same b). X fragments + ||x||^2 built
// during the single latents read; W fragments stream from L1/L2 (64 KB).
// acc[r] = ||w_k||^2 + 2 - 2 x.w_k  for k = k0 + g*4 + r, pos = pt*16 + c.
// Packed argmin: u32 = (score_bits & ~511) | k; min_u32; strict-min keeps
// smallest k on masked-score ties (jnp.argmin tie-break up to bf16 noise).
__global__ __launch_bounds__(256) void fused_vq_kernel(
    const float* __restrict__ latents, const unsigned short* __restrict__ wbf,
    const float* __restrict__ wwb, const float* __restrict__ embT,
    float* __restrict__ out, float* __restrict__ partial) {
    const int tid  = threadIdx.x;
    const int wave = tid >> 6;
    const int l    = tid & 63;
    const int c    = l & 15;   // tile col (position) / A row (k)
    const int g    = l >> 4;   // k-slot group

    const int n0  = blockIdx.x * 128 + wave * 32;
    const int b   = n0 >> 10;
    const int hw0 = n0 & 1023;
    const float* xbase = latents + (size_t)b * (DIM * HW) + hw0;

    // ---- load x: bf16 fragments for MFMA, f32 ||x||^2 partial for loss ----
    float x2 = 0.f;
    bf16x8 xf[2][2];
#pragma unroll
    for (int pt = 0; pt < 2; ++pt) {
#pragma unroll
        for (int f = 0; f < 2; ++f) {
            const int d0 = f * 32 + g * 8;
            const int p  = pt * 16 + c;
            bf16x8 v;
#pragma unroll
            for (int j = 0; j < 8; ++j) {
                const float xv = xbase[(d0 + j) * HW + p];
                x2 = fmaf(xv, xv, x2);
                v[j] = (short)f32_to_bf16_rne(xv);
            }
            xf[pt][f] = v;
        }
    }

    // ---- MFMA argmin over 512 codes ----
    unsigned int best0 = 0xFFFFFFFFu, best1 = 0xFFFFFFFFu;
    const unsigned short* wp = wbf + c * DIM + g * 8;
    const float* wwp = wwb + g * 4;

#pragma unroll 4
    for (int k0 = 0; k0 < NUM_EMB; k0 += 16) {
        bf16x8 a0 = *(const bf16x8*)(wp);
        bf16x8 a1 = *(const bf16x8*)(wp + 32);
        f32x4 ww4 = *(const f32x4*)(wwp);
        wp  += 16 * DIM;
        wwp += 16;

        f32x4 acc0 = __builtin_amdgcn_mfma_f32_16x16x32_bf16(a0, xf[0][0], ww4, 0, 0, 0);
        acc0       = __builtin_amdgcn_mfma_f32_16x16x32_bf16(a1, xf[0][1], acc0, 0, 0, 0);
        f32x4 acc1 = __builtin_amdgcn_mfma_f32_16x16x32_bf16(a0, xf[1][0], ww4, 0, 0, 0);
        acc1       = __builtin_amdgcn_mfma_f32_16x16x32_bf16(a1, xf[1][1], acc1, 0, 0, 0);

        const unsigned int kb = (unsigned int)(k0 + g * 4);
#pragma unroll
        for (int r = 0; r < 4; ++r) {
            unsigned int t0 = (__builtin_bit_cast(unsigned int, acc0[r]) & 0xFFFFFE00u) | (kb + r);
            best0 = t0 < best0 ? t0 : best0;
            unsigned int t1 = (__builtin_bit_cast(unsigned int, acc1[r]) & 0xFFFFFE00u) | (kb + r);
            best1 = t1 < best1 ? t1 : best1;
        }
    }
    // reduce over the 4 k-groups; afterwards ALL lanes hold the global min
    unsigned int o;
    o = __shfl_xor(best0, 16); best0 = o < best0 ? o : best0;
    o = __shfl_xor(best0, 32); best0 = o < best0 ? o : best0;
    o = __shfl_xor(best1, 16); best1 = o < best1 ? o : best1;
    o = __shfl_xor(best1, 32); best1 = o < best1 ? o : best1;

    // ---- loss partial: sum_d (q-x)^2 = (score - 2) + ||x||^2 ----
    // best0/best1 are replicated across the 4 g-copies -> weight scores by 1/4.
    const float s0 = __builtin_bit_cast(float, best0 & 0xFFFFFE00u);
    const float s1 = __builtin_bit_cast(float, best1 & 0xFFFFFE00u);
    float contrib = x2 + 0.25f * ((s0 - 2.0f) + (s1 - 2.0f));
#pragma unroll
    for (int off = 32; off; off >>= 1) contrib += __shfl_xor(contrib, off, 64);
    __shared__ float wsum[4];
    if (l == 0) wsum[wave] = contrib;

    // ---- write quantized output, coalesced float4, gather L1-hot embT ----
    // lane l owns positions p4..p4+3 (p4=(l&7)*4) at d-rows (l>>3) + 8*i.
    const int p4 = (l & 7) * 4;
    int k4[4];
#pragma unroll
    for (int i = 0; i < 4; ++i) {
        const int p = p4 + i;
        const unsigned lo = __shfl(best0, p & 15);
        const unsigned hi = __shfl(best1, p & 15);
        k4[i] = (int)(((p < 16) ? lo : hi) & 511u);
    }
    const int drow = l >> 3;
    float* obase = out + (size_t)b * (DIM * HW) + hw0 + p4;
#pragma unroll
    for (int i = 0; i < 8; ++i) {
        const int d = i * 8 + drow;
        const float* er = embT + (d << 9);
        float4 q;
        q.x = er[k4[0]]; q.y = er[k4[1]]; q.z = er[k4[2]]; q.w = er[k4[3]];
        *(float4*)(obase + d * HW) = q;
    }

    __syncthreads();
    if (tid == 0)
        partial[blockIdx.x] = (wsum[0] + wsum[1]) + (wsum[2] + wsum[3]);
}

__global__ __launch_bounds__(256) void finalize_kernel(
    const float* __restrict__ partial, float* __restrict__ out) {
    double s = (double)partial[threadIdx.x] + (double)partial[threadIdx.x + 256];
#pragma unroll
    for (int off = 32; off; off >>= 1) s += __shfl_xor(s, off, 64);
    __shared__ double dsum[4];
    if ((threadIdx.x & 63) == 0) dsum[threadIdx.x >> 6] = s;
    __syncthreads();
    if (threadIdx.x == 0) {
        const double tot = (dsum[0] + dsum[1]) + (dsum[2] + dsum[3]);
        out[TOTAL] = (float)(1.25 * tot / (double)TOTAL);
    }
}

extern "C" void kernel_launch(void* const* d_in, const int* in_sizes, int n_in,
                              void* d_out, int out_size, void* d_ws, size_t ws_size,
                              hipStream_t stream) {
    const float* latents = (const float*)d_in[0];
    const float* emb     = (const float*)d_in[1];
    float* out = (float*)d_out;

    unsigned short* wbf     = (unsigned short*)d_ws;
    float*          wwb     = (float*)((char*)d_ws + 65536);
    float*          embT    = (float*)((char*)d_ws + 67584);
    float*          partial = (float*)((char*)d_ws + 198656);

    prep_kernel<<<128, 256, 0, stream>>>(emb, wbf, wwb, embT);
    fused_vq_kernel<<<FUSED_BLOCKS, 256, 0, stream>>>(latents, wbf, wwb, embT, out, partial);
    finalize_kernel<<<1, 256, 0, stream>>>(partial, out);
}